// Round 11
// baseline (2278.108 us; speedup 1.0000x reference)
//
#include <hip/hip_runtime.h>

// ---------------------------------------------------------------------------
// Sparse 3D conv backbone.
// Gather convs: per-wave LDS tile inverse map built UP FRONT (all taps, one
// lgkmcnt fence), then branch-free compute (LDS read -> sentinel zero-row ->
// unconditional load -> FMA/MFMA). Small per-wave LDS footprint for occupancy:
//   rb2 MFMA conv: 1 wave = one 16-row tile, block = 4 waves = 64 rows (8KB).
//   stage-1 conv : 1 wave = 64 rows, block = 2 waves = 128 rows (14KB).
// Stage 1 fp32 (exact top-k mask), stage 2 bf16 MFMA, XCD-swizzled blocks.
// ---------------------------------------------------------------------------

typedef __attribute__((ext_vector_type(8))) short bf16x8;
typedef __attribute__((ext_vector_type(4))) float f32x4;

static __device__ __forceinline__ unsigned f2bfu(float x) {   // fp32->bf16 RNE
    unsigned b = __float_as_uint(x);
    return (b + 0x7FFFu + ((b >> 16) & 1u)) >> 16;
}
static __device__ __forceinline__ float bf2f(unsigned short u) {
    return __uint_as_float(((unsigned)u) << 16);
}
// bijective XCD swizzle: round-robin dispatch -> contiguous chunk per XCD
static __device__ __forceinline__ int xcd_swz(int bid, int nwg) {
    if (nwg < 16) return bid;
    int q = nwg >> 3, r = nwg & 7;
    int x = bid & 7, i = bid >> 3;
    return (x < r ? x * (q + 1) : r * (q + 1) + (x - r) * q) + i;
}

__global__ void rb_count_kernel(const int* __restrict__ rout, int P, int n_out,
                                int* __restrict__ cnt) {
    int k = threadIdx.x;
    if (k >= 27) return;
    const int* r = rout + (size_t)k * P;
    int lo = 0, hi = P;
    while (lo < hi) {
        int mid = (lo + hi) >> 1;
        if (r[mid] < n_out) lo = mid + 1; else hi = mid;
    }
    cnt[k] = lo;
}

// segs[k][b] = lower_bound(rout[k], b*gran), b in [0, nb]
__global__ void seg_build(const int* __restrict__ rout, const int* __restrict__ cnt,
                          int P, int nb, int gran, int* __restrict__ segs) {
    const int k = blockIdx.y;
    const int b = blockIdx.x * 256 + threadIdx.x;
    if (b > nb) return;
    const int target = b * gran;
    const int* r = rout + (size_t)k * P;
    int lo = 0, hi = cnt[k];
    while (lo < hi) {
        int m = (lo + hi) >> 1;
        if (r[m] < target) lo = m + 1; else hi = m;
    }
    segs[k * (nb + 1) + b] = lo;
}

__global__ void inv_build(const int* __restrict__ rin, const int* __restrict__ rout,
                          const int* __restrict__ cnt, int P, int n_out,
                          int* __restrict__ inv) {
    const int k = blockIdx.y;
    const int p = blockIdx.x * 256 + threadIdx.x;
    if (p < cnt[k])
        inv[(size_t)k * n_out + rout[(size_t)k * P + p]] = rin[(size_t)k * P + p];
}

// Pre-pack fp32 weights [T][CI][32] into MFMA B-frag bf16 order.
__global__ void prepack_w(const float* __restrict__ W, int T, int CI, int S,
                          short* __restrict__ pack) {
    int idx = blockIdx.x * 256 + threadIdx.x;     // over S*128
    if (idx >= S * 128) return;
    int l = idx & 63, h = (idx >> 6) & 1, s = idx >> 7;
    int co = (l & 15) + 16 * h;
#pragma unroll
    for (int j = 0; j < 8; j++) {
        int gk = s * 32 + (l >> 4) * 8 + j;
        int tap = gk / CI, cin = gk % CI;
        float w = (tap < T) ? W[((size_t)tap * CI + cin) * 32 + co] : 0.f;
        pack[(size_t)idx * 8 + j] = (short)f2bfu(w);
    }
}

// ---- MFMA gather conv, sorted rulebook, bf16 feat [n+1][32] (zero row @n) --
// One wave = one 16-row tile; block = 4 waves = 64 rows. Full 27-tap inverse
// map built up front (one lgkm fence), then branch-free unrolled MFMA loop.
template <bool OUT_BF16>
__global__ __launch_bounds__(256) void conv_mfma_t16(
        const unsigned short* __restrict__ feat, const short* __restrict__ Bp,
        const int* __restrict__ rin, const int* __restrict__ rout,
        const int* __restrict__ segs, int P, int nb16, int n_out,
        void* __restrict__ outv, float* __restrict__ stats) {
    __shared__ int invt[4][432];              // [wave][k*16 + slot]
    __shared__ float part[2][4][32];
    const int t = threadIdx.x, wv = t >> 6, lane = t & 63;
    const int row = lane & 15, grp = lane >> 4;
    const int bid = xcd_swz(blockIdx.x, gridDim.x);
    const int rowbase = bid * 64 + wv * 16;
    const bool active = rowbase < n_out;
    float ss0 = 0.f, qq0 = 0.f, ss1 = 0.f, qq1 = 0.f;

    if (active) {
        const int tix = rowbase >> 4;
        int segv = 0;
        if (lane < 28)      segv = segs[lane * (nb16 + 1) + tix];
        else if (lane < 56) segv = segs[(lane - 28) * (nb16 + 1) + tix + 1];
        // init map (432 ints = 108 int4)
        int4* ip = (int4*)invt[wv];
#pragma unroll
        for (int c = 0; c < 2; ++c) {
            const int idx = c * 64 + lane;
            if (idx < 108) ip[idx] = make_int4(-1, -1, -1, -1);
        }
        // scatter all 27 taps: 7 rounds x (4 taps x 16 slots)
#pragma unroll
        for (int c = 0; c < 7; ++c) {
            const int k = c * 4 + grp;
            const int kc = min(k, 26);
            const int s0 = __shfl(segv, kc);
            const int s1 = __shfl(segv, 28 + kc);
            const int e = s0 + row;
            if (k < 27 && e < s1)                // segment len <= 16 (unique routs)
                invt[wv][k * 16 + (rout[(size_t)k * P + e] - rowbase)] =
                    rin[(size_t)k * P + e];
        }
        asm volatile("s_waitcnt lgkmcnt(0)" ::: "memory");

        f32x4 d0 = {0.f, 0.f, 0.f, 0.f}, d1 = {0.f, 0.f, 0.f, 0.f};
#pragma unroll
        for (int k = 0; k < 27; ++k) {
            int rn = invt[wv][k * 16 + row];
            rn = (rn >= 0) ? rn : n_out;                 // sentinel zero row
            union { int u[4]; bf16x8 v; } ua;
            ua.v = *(const bf16x8*)(feat + (size_t)rn * 32 + grp * 8);
            const bf16x8 b0 = *(const bf16x8*)(Bp + ((size_t)(2 * k) * 64 + lane) * 8);
            const bf16x8 b1 = *(const bf16x8*)(Bp + ((size_t)(2 * k + 1) * 64 + lane) * 8);
            d0 = __builtin_amdgcn_mfma_f32_16x16x32_bf16(ua.v, b0, d0, 0, 0, 0);
            d1 = __builtin_amdgcn_mfma_f32_16x16x32_bf16(ua.v, b1, d1, 0, 0, 0);
        }
        const int m0 = rowbase + grp * 4;
#pragma unroll
        for (int i = 0; i < 4; i++) {
            if (m0 + i < n_out) {
                if (OUT_BF16) {
                    unsigned short* o = (unsigned short*)outv;
                    o[(size_t)(m0 + i) * 32 + row]      = (unsigned short)f2bfu(d0[i]);
                    o[(size_t)(m0 + i) * 32 + row + 16] = (unsigned short)f2bfu(d1[i]);
                } else {
                    float* o = (float*)outv;
                    o[(size_t)(m0 + i) * 32 + row]      = d0[i];
                    o[(size_t)(m0 + i) * 32 + row + 16] = d1[i];
                }
            }
            ss0 += d0[i]; qq0 += d0[i] * d0[i];
            ss1 += d1[i]; qq1 += d1[i] * d1[i];
        }
    }
#pragma unroll
    for (int d = 16; d <= 32; d <<= 1) {
        ss0 += __shfl_xor(ss0, d); qq0 += __shfl_xor(qq0, d);
        ss1 += __shfl_xor(ss1, d); qq1 += __shfl_xor(qq1, d);
    }
    if (lane < 16) {
        part[0][wv][row] = ss0; part[0][wv][row + 16] = ss1;
        part[1][wv][row] = qq0; part[1][wv][row + 16] = qq1;
    }
    __syncthreads();
    if (t < 64) {
        const int which = t >> 5, co = t & 31;
        atomicAdd(&stats[which * 32 + co],
                  part[which][0][co] + part[which][1][co] +
                  part[which][2][co] + part[which][3][co]);
    }
}

// ---- MFMA conv, dense inverse map, CIN=16 (2 taps/step) COUT=32 -----------
// feat (bf16 [*][16]) has zero row at index nzero.
__global__ __launch_bounds__(256) void conv_mfma_inv16(
        const unsigned short* __restrict__ feat, const short* __restrict__ Bp,
        const int* __restrict__ inv, int n_out, int nzero,
        unsigned short* __restrict__ out, float* __restrict__ stats) {
    __shared__ float part[2][4][32];
    const int t = threadIdx.x, wv = t >> 6, lane = t & 63;
    const int row = lane & 15, grp = lane >> 4;
    const int bid = xcd_swz(blockIdx.x, gridDim.x);
    float ss0 = 0.f, qq0 = 0.f, ss1 = 0.f, qq1 = 0.f;

    for (int tile = 0; tile < 4; ++tile) {
        const int rowbase = bid * 256 + wv * 64 + tile * 16;
        if (rowbase >= n_out) break;
        const int j = rowbase + row;
        const int jm = min(j, n_out - 1);
        const bool jv = j < n_out;
        f32x4 d0 = {0.f, 0.f, 0.f, 0.f}, d1 = {0.f, 0.f, 0.f, 0.f};
#pragma unroll
        for (int s = 0; s < 14; ++s) {
            const int tap = 2 * s + (grp >> 1);
            const int cin0 = (grp & 1) * 8;
            const int tapc = min(tap, 26);
            int rn = inv[(size_t)tapc * n_out + jm];
            rn = (jv && tap < 27 && rn >= 0) ? rn : nzero;
            union { int u[4]; bf16x8 v; } ua;
            ua.v = *(const bf16x8*)(feat + (size_t)rn * 16 + cin0);
            const bf16x8 b0 = *(const bf16x8*)(Bp + ((size_t)(2 * s) * 64 + lane) * 8);
            const bf16x8 b1 = *(const bf16x8*)(Bp + ((size_t)(2 * s + 1) * 64 + lane) * 8);
            d0 = __builtin_amdgcn_mfma_f32_16x16x32_bf16(ua.v, b0, d0, 0, 0, 0);
            d1 = __builtin_amdgcn_mfma_f32_16x16x32_bf16(ua.v, b1, d1, 0, 0, 0);
        }
        const int m0 = rowbase + grp * 4;
#pragma unroll
        for (int i = 0; i < 4; i++) {
            if (m0 + i < n_out) {
                out[(size_t)(m0 + i) * 32 + row]      = (unsigned short)f2bfu(d0[i]);
                out[(size_t)(m0 + i) * 32 + row + 16] = (unsigned short)f2bfu(d1[i]);
            }
            ss0 += d0[i]; qq0 += d0[i] * d0[i];
            ss1 += d1[i]; qq1 += d1[i] * d1[i];
        }
    }
#pragma unroll
    for (int d = 16; d <= 32; d <<= 1) {
        ss0 += __shfl_xor(ss0, d); qq0 += __shfl_xor(qq0, d);
        ss1 += __shfl_xor(ss1, d); qq1 += __shfl_xor(qq1, d);
    }
    if (lane < 16) {
        part[0][wv][row] = ss0; part[0][wv][row + 16] = ss1;
        part[1][wv][row] = qq0; part[1][wv][row + 16] = qq1;
    }
    __syncthreads();
    if (t < 64) {
        const int which = t >> 5, co = t & 31;
        atomicAdd(&stats[which * 32 + co],
                  part[which][0][co] + part[which][1][co] +
                  part[which][2][co] + part[which][3][co]);
    }
}

// ---- fp32 wave-tile conv, CIN=16: full map up front, one fence ------------
// 2 waves/block (128 threads), each wave owns 64 rows. feat zero row @nzero.
template <int COUT, bool SIGMOID, bool STATS>
__global__ __launch_bounds__(128) void conv16_tile(
        const float* __restrict__ feat, const float* __restrict__ W,
        const int* __restrict__ rin, const int* __restrict__ rout,
        const int* __restrict__ segs, int P, int nb64, int n_out, int nzero,
        float* __restrict__ out, float* __restrict__ stats) {
    __shared__ int invt[2][27 * 64];
    __shared__ float part[2][2][COUT];
    const int t = threadIdx.x, wv = t >> 6, lane = t & 63;
    const int bid = xcd_swz(blockIdx.x, gridDim.x);
    const int rowbase = bid * 128 + wv * 64;
    const bool active = rowbase < n_out;
    float acc[COUT];
#pragma unroll
    for (int co = 0; co < COUT; co++) acc[co] = 0.f;

    if (active) {
        const int tix = rowbase >> 6;
        int segv = 0;
        if (lane < 28)      segv = segs[lane * (nb64 + 1) + tix];
        else if (lane < 56) segv = segs[(lane - 28) * (nb64 + 1) + tix + 1];
        // init 27*64 ints = 432 int4
        int4* ip = (int4*)invt[wv];
#pragma unroll
        for (int c = 0; c < 7; ++c) {
            const int idx = c * 64 + lane;
            if (idx < 432) ip[idx] = make_int4(-1, -1, -1, -1);
        }
        // scatter all 27 taps (independent rounds)
#pragma unroll
        for (int k = 0; k < 27; ++k) {
            const int s0 = __shfl(segv, k);
            const int s1 = __shfl(segv, 28 + k);
            const int e = s0 + lane;             // segment len <= 64
            if (e < s1)
                invt[wv][k * 64 + (rout[(size_t)k * P + e] - rowbase)] =
                    rin[(size_t)k * P + e];
        }
        asm volatile("s_waitcnt lgkmcnt(0)" ::: "memory");
        // branch-free compute
#pragma unroll 2
        for (int k = 0; k < 27; ++k) {
            int rn = invt[wv][k * 64 + lane];
            rn = (rn >= 0) ? rn : nzero;         // sentinel zero row
            const float* fr = feat + (size_t)rn * 16;
            float f[16];
#pragma unroll
            for (int q = 0; q < 4; q++) {
                const float4 v = *(const float4*)(fr + 4 * q);
                f[4 * q] = v.x; f[4 * q + 1] = v.y;
                f[4 * q + 2] = v.z; f[4 * q + 3] = v.w;
            }
            const float* __restrict__ Wk = W + k * 16 * COUT;   // lane-uniform
#pragma unroll
            for (int ci = 0; ci < 16; ci++) {
                const float fv = f[ci];
#pragma unroll
                for (int co = 0; co < COUT; co++)
                    acc[co] = fmaf(fv, Wk[ci * COUT + co], acc[co]);
            }
        }
        const int j = rowbase + lane;
        if (j < n_out) {
#pragma unroll
            for (int co = 0; co < COUT; co++) {
                float v = acc[co];
                if (SIGMOID) v = 1.f / (1.f + expf(-v));
                out[(size_t)j * COUT + co] = v;
            }
        }
    }
    if (STATS) {
#pragma unroll
        for (int co = 0; co < COUT; co++) {
            float s = acc[co], s2 = s * s;
#pragma unroll
            for (int d = 1; d < 64; d <<= 1) {
                s += __shfl_xor(s, d);
                s2 += __shfl_xor(s2, d);
            }
            if (lane == 0) { part[0][wv][co] = s; part[1][wv][co] = s2; }
        }
        __syncthreads();
        if (t < 2 * COUT) {
            const int which = t / COUT, co = t - which * COUT;
            atomicAdd(&stats[which * COUT + co],
                      part[which][0][co] + part[which][1][co]);
        }
    }
}

// ---- fp32 block gather conv (conv_input 5->16 only) -----------------------
template <int CIN, int COUT>
__global__ __launch_bounds__(256) void conv_gather(
        const float* __restrict__ feat, const float* __restrict__ W,
        const int* __restrict__ rin, const int* __restrict__ rout,
        const int* __restrict__ segs, int P, int n_out,
        float* __restrict__ out, float* __restrict__ stats) {
    __shared__ int2 invl[256];        // {tag k, rin}; valid iff tag == k
    __shared__ int seg[54];
    __shared__ float part[2][4][COUT];
    const int t = threadIdx.x;
    const int bid = xcd_swz(blockIdx.x, gridDim.x);
    const int j0 = bid * 256;
    const int nb1 = gridDim.x + 1;
    if (t < 54) seg[t] = segs[(t >> 1) * nb1 + bid + (t & 1)];
    invl[t] = make_int2(-1, -1);
    float acc[COUT];
#pragma unroll
    for (int co = 0; co < COUT; co++) acc[co] = 0.f;
    __syncthreads();

    for (int k = 0; k < 27; k++) {
        const int s0 = seg[2 * k], s1 = seg[2 * k + 1];
        if (s0 == s1) continue;
        const int idx = s0 + t;
        if (idx < s1)
            invl[rout[(size_t)k * P + idx] - j0] = make_int2(k, rin[(size_t)k * P + idx]);
        __syncthreads();
        const int2 e = invl[t];
        const int in = (e.x == k) ? e.y : -1;
        __syncthreads();

        float f[CIN];
#pragma unroll
        for (int ci = 0; ci < CIN; ci++) f[ci] = 0.f;
        if (in >= 0) {
            const float* fr = feat + (size_t)in * CIN;
#pragma unroll
            for (int ci = 0; ci < CIN; ci++) f[ci] = fr[ci];
        }
        const float* __restrict__ Wk = W + k * CIN * COUT;   // lane-uniform
#pragma unroll
        for (int ci = 0; ci < CIN; ci++) {
            const float fv = f[ci];
#pragma unroll
            for (int co = 0; co < COUT; co++)
                acc[co] = fmaf(fv, Wk[ci * COUT + co], acc[co]);
        }
    }

    const int j = j0 + t;
    if (j < n_out) {
#pragma unroll
        for (int co = 0; co < COUT; co++) out[(size_t)j * COUT + co] = acc[co];
    }
    const int wv = t >> 6, lane = t & 63;
#pragma unroll
    for (int co = 0; co < COUT; co++) {
        float s = acc[co], s2 = s * s;
#pragma unroll
        for (int d = 1; d < 64; d <<= 1) {
            s += __shfl_xor(s, d);
            s2 += __shfl_xor(s2, d);
        }
        if (lane == 0) { part[0][wv][co] = s; part[1][wv][co] = s2; }
    }
    __syncthreads();
    if (t < 2 * COUT) {
        const int which = t / COUT, co = t - which * COUT;
        atomicAdd(&stats[which * COUT + co],
                  part[which][0][co] + part[which][1][co] +
                  part[which][2][co] + part[which][3][co]);
    }
}

template <int C, bool RELU>
__global__ void bn_apply(const float* __restrict__ x, const float* __restrict__ stats,
                         const float* __restrict__ gg, const float* __restrict__ bb,
                         int n, float* __restrict__ y) {
    const float nf = (float)n;
    const long long total = (long long)n * C;
    for (long long idx = (long long)blockIdx.x * blockDim.x + threadIdx.x;
         idx < total; idx += (long long)gridDim.x * blockDim.x) {
        int ch = (int)(idx & (C - 1));
        float m = stats[ch] / nf;
        float v = stats[C + ch] / nf - m * m;
        float r = rsqrtf(v + 1e-3f);
        float val = gg[ch] * (x[idx] - m) * r + bb[ch];
        if (RELU) val = fmaxf(val, 0.f);
        y[idx] = val;
    }
}

template <int C>
__global__ void bn_apply_addrelu(const float* __restrict__ x,
                                 const float* __restrict__ skip,
                                 const float* __restrict__ stats,
                                 const float* __restrict__ gg,
                                 const float* __restrict__ bb,
                                 int n, float* __restrict__ y) {
    const float nf = (float)n;
    const long long total = (long long)n * C;
    for (long long idx = (long long)blockIdx.x * blockDim.x + threadIdx.x;
         idx < total; idx += (long long)gridDim.x * blockDim.x) {
        int ch = (int)(idx & (C - 1));
        float m = stats[ch] / nf;
        float v = stats[C + ch] / nf - m * m;
        float r = rsqrtf(v + 1e-3f);
        float val = gg[ch] * (x[idx] - m) * r + bb[ch] + skip[idx];
        y[idx] = fmaxf(val, 0.f);
    }
}

// BN over bf16 in -> bf16 out (stage-2 feature buffers)
template <int C>
__global__ void bn_apply_b(const unsigned short* __restrict__ x,
                           const float* __restrict__ stats,
                           const float* __restrict__ gg, const float* __restrict__ bb,
                           int n, unsigned short* __restrict__ y) {
    const float nf = (float)n;
    const long long total = (long long)n * C;
    for (long long idx = (long long)blockIdx.x * blockDim.x + threadIdx.x;
         idx < total; idx += (long long)gridDim.x * blockDim.x) {
        int ch = (int)(idx & (C - 1));
        float m = stats[ch] / nf;
        float v = stats[C + ch] / nf - m * m;
        float r = rsqrtf(v + 1e-3f);
        float val = gg[ch] * (bf2f(x[idx]) - m) * r + bb[ch];
        val = fmaxf(val, 0.f);
        y[idx] = (unsigned short)f2bfu(val);
    }
}

// BN(x) + bf16 skip + ReLU; x bf16 or fp32, out bf16 or fp32
template <int C, bool XBF16, bool OUT_BF16>
__global__ void bn_addrelu_x(const void* __restrict__ xv,
                             const unsigned short* __restrict__ skip,
                             const float* __restrict__ stats,
                             const float* __restrict__ gg,
                             const float* __restrict__ bb,
                             int n, void* __restrict__ yv) {
    const float nf = (float)n;
    const long long total = (long long)n * C;
    for (long long idx = (long long)blockIdx.x * blockDim.x + threadIdx.x;
         idx < total; idx += (long long)gridDim.x * blockDim.x) {
        int ch = (int)(idx & (C - 1));
        float m = stats[ch] / nf;
        float v = stats[C + ch] / nf - m * m;
        float r = rsqrtf(v + 1e-3f);
        float x = XBF16 ? bf2f(((const unsigned short*)xv)[idx])
                        : ((const float*)xv)[idx];
        float val = gg[ch] * (x - m) * r + bb[ch] + bf2f(skip[idx]);
        val = fmaxf(val, 0.f);
        if (OUT_BF16) ((unsigned short*)yv)[idx] = (unsigned short)f2bfu(val);
        else          ((float*)yv)[idx] = val;
    }
}

// ---- exact top-k: 4-pass byte radix, LDS-privatized histograms ------------
__global__ __launch_bounds__(256) void hist_pass(const float* __restrict__ imp, int n,
                                                 int pass, const int* __restrict__ state,
                                                 int* __restrict__ hist) {
    __shared__ int lh[256];
    const int t = threadIdx.x;
    lh[t] = 0;
    __syncthreads();
    const int shift = 24 - 8 * pass;
    unsigned prefix = 0;
    if (pass > 0) prefix = (unsigned)state[0];
    for (int i = blockIdx.x * 256 + t; i < n; i += gridDim.x * 256) {
        unsigned u = __float_as_uint(imp[i]);
        if (pass == 0 || (u >> (shift + 8)) == prefix)
            atomicAdd(&lh[(u >> shift) & 0xFFu], 1);
    }
    __syncthreads();
    if (lh[t]) atomicAdd(&hist[pass * 256 + t], lh[t]);
}

__global__ __launch_bounds__(256) void scan_byte(const int* __restrict__ hist,
                                                 int kkeep, int pass,
                                                 int* __restrict__ state) {
    __shared__ int h[256];
    const int t = threadIdx.x;
    h[t] = hist[pass * 256 + t];
    __syncthreads();
    if (t == 0) {
        const int target = (pass == 0) ? kkeep : state[1];
        int acc = 0; int b = 255;
        for (; b > 0; b--) {
            if (acc + h[b] >= target) break;
            acc += h[b];
        }
        unsigned prefix = (pass == 0) ? 0u : (unsigned)state[0];
        prefix = (prefix << 8) | (unsigned)b;
        state[0] = (int)prefix;
        state[1] = target - acc;
        if (pass == 3) state[2] = (int)prefix;   // exact bits of kth largest
    }
}

// prune + emit bf16 pruned features (Ab) in one pass; fp32 A dies here
__global__ void prune_mask_ab(const float* __restrict__ x, const float* __restrict__ imp,
                              const int* __restrict__ state, int n,
                              unsigned short* __restrict__ ab) {
    const unsigned K = (unsigned)state[2];
    int i = blockIdx.x * blockDim.x + threadIdx.x;
    if (i >= n) return;
    float im = imp[i];
    float mult = (__float_as_uint(im) >= K) ? im : 0.f;
#pragma unroll
    for (int c = 0; c < 16; c++)
        ab[(size_t)i * 16 + c] = (unsigned short)f2bfu(x[(size_t)i * 16 + c] * mult);
}

extern "C" void kernel_launch(void* const* d_in, const int* in_sizes, int n_in,
                              void* d_out, int out_size, void* d_ws, size_t ws_size,
                              hipStream_t stream) {
    const float* vf    = (const float*)d_in[0];
    const float* W_in  = (const float*)d_in[1];
    const float* g_in  = (const float*)d_in[2];
    const float* b_in  = (const float*)d_in[3];
    const float* Wb1   = (const float*)d_in[4];
    const float* gb1   = (const float*)d_in[6];
    const float* beb1  = (const float*)d_in[7];
    const float* Wp    = (const float*)d_in[8];
    const float* Wd    = (const float*)d_in[9];
    const float* g_d   = (const float*)d_in[10];
    const float* b_d   = (const float*)d_in[11];
    const float* Wb2   = (const float*)d_in[12];
    const float* gb2   = (const float*)d_in[14];
    const float* beb2  = (const float*)d_in[15];
    const int* rb1_in  = (const int*)d_in[16];
    const int* rb1_out = (const int*)d_in[17];
    const int* rbd_in  = (const int*)d_in[18];
    const int* rbd_out = (const int*)d_in[19];
    const int* rb2_in  = (const int*)d_in[20];
    const int* rb2_out = (const int*)d_in[21];

    const int N  = in_sizes[0] / 5;
    const int P1 = in_sizes[16] / 27;
    const int Pd = in_sizes[18] / 27;
    const int P2 = in_sizes[20] / 27;
    const int n2 = out_size / 32;
    const int kkeep = N - N / 2;

    const int gs1   = (N + 255) / 256;        // 256-row blocks over N (conv_input)
    const int gsw   = (N + 127) / 128;        // 128-row blocks (conv16_tile)
    const int gm2   = (n2 + 255) / 256;       // 256-row blocks (conv_mfma_inv16)
    const int gmt   = (n2 + 63) / 64;         // 64-row blocks (conv_mfma_t16)
    const int nb64  = (N + 63) / 64;          // 64-row tiles over N
    const int nb16  = (n2 + 15) / 16;         // 16-row tiles over n2
    const int gew   = 2048;

    // workspace layout (4-byte words); regions 16B-aligned
    auto pad4 = [](size_t v) { return (v + 3) & ~(size_t)3; };
    float* A     = (float*)d_ws;                       // (N+1) x 16 fp32 (zero row @N)
    float* B     = A   + pad4((size_t)N * 16 + 16);    // (N+1) x 16 fp32 (Ab+segs16 later)
    float* imp   = B   + pad4((size_t)N * 16 + 16);    // N (packs later)
    float* INVf  = imp + pad4((size_t)N);              // 27*n2 ints (invd only)
    float* Dbf   = INVf + pad4((size_t)n2 * 27);       // (n2+1) x 32 bf16
    float* Ebf   = Dbf + pad4((size_t)n2 * 16 + 16);   // (n2+1) x 32 bf16
    float* stats = Ebf + pad4((size_t)n2 * 16 + 16);   // 64
    int*   cnt1  = (int*)(stats + 64);
    int*   cntd  = cnt1 + 32;
    int*   cnt2  = cntd + 32;
    int*   hist4 = cnt2 + 32;                          // 4 * 256
    int*   state = hist4 + 1024;                       // 8
    int*   segs1 = state + 8;                          // 27 * (gs1+1)
    int*   segs64 = segs1 + 27 * (gs1 + 1);            // 27 * (nb64+1)
    int*   INV    = (int*)INVf;                        // invd (rbd dense inverse)
    unsigned short* Ab = (unsigned short*)B;           // (N+1) x 16 bf16 (B dead)
    int*   segs16 = (int*)(B + pad4((size_t)(N + 1) * 8));  // in B tail (after Ab)
    short* pack2  = (short*)imp;                       // 4 * 27648 shorts (imp dead)
    short* packd  = pack2 + 4 * 27648;                 // 14336 shorts
    unsigned short* Db = (unsigned short*)Dbf;
    unsigned short* Eb = (unsigned short*)Ebf;
    float* OUT   = (float*)d_out;
    unsigned short* OUTb = (unsigned short*)d_out;     // bf16 scratch in d_out
    float* C2    = OUT;                                // stage-1 scratch (16N <= 32n2)

    rb_count_kernel<<<1, 32, 0, stream>>>(rb1_out, P1, N,  cnt1);
    rb_count_kernel<<<1, 32, 0, stream>>>(rbd_out, Pd, n2, cntd);
    rb_count_kernel<<<1, 32, 0, stream>>>(rb2_out, P2, n2, cnt2);
    seg_build<<<dim3((gs1 + 256) / 256, 27), 256, 0, stream>>>(rb1_out, cnt1, P1, gs1, 256, segs1);
    seg_build<<<dim3((nb64 + 256) / 256, 27), 256, 0, stream>>>(rb1_out, cnt1, P1, nb64, 64, segs64);

    // zero sentinel rows for stage-1 gather buffers
    hipMemsetAsync(A + (size_t)N * 16, 0, 64, stream);
    hipMemsetAsync(B + (size_t)N * 16, 0, 64, stream);

    // ---- stage 1 (fp32): conv_input + BN + ReLU -> A
    hipMemsetAsync(stats, 0, 64 * 4, stream);
    conv_gather<5, 16><<<gs1, 256, 0, stream>>>(vf, W_in, rb1_in, rb1_out, segs1, P1, N, B, stats);
    bn_apply<16, true><<<gew, 256, 0, stream>>>(B, stats, g_in, b_in, N, A);

    for (int i = 0; i < 2; i++) {
        const float* W0 = Wb1 + (size_t)(i * 2 + 0) * 27 * 256;
        const float* W1 = Wb1 + (size_t)(i * 2 + 1) * 27 * 256;
        hipMemsetAsync(stats, 0, 64 * 4, stream);
        conv16_tile<16, false, true><<<gsw, 128, 0, stream>>>(A, W0, rb1_in, rb1_out, segs64, P1, nb64, N, N, B, stats);
        bn_apply<16, true><<<gew, 256, 0, stream>>>(B, stats, gb1 + (i * 2 + 0) * 16, beb1 + (i * 2 + 0) * 16, N, B);
        hipMemsetAsync(stats, 0, 64 * 4, stream);
        conv16_tile<16, false, true><<<gsw, 128, 0, stream>>>(B, W1, rb1_in, rb1_out, segs64, P1, nb64, N, N, C2, stats);
        bn_apply_addrelu<16><<<gew, 256, 0, stream>>>(C2, A, stats, gb1 + (i * 2 + 1) * 16, beb1 + (i * 2 + 1) * 16, N, A);
    }

    // ---- pruning: imp = sigmoid(conv 16->1); exact top-k via byte radix
    conv16_tile<1, true, false><<<gsw, 128, 0, stream>>>(A, Wp, rb1_in, rb1_out, segs64, P1, nb64, N, N, imp, stats);
    hipMemsetAsync(hist4, 0, 1024 * 4, stream);
    for (int p = 0; p < 4; p++) {
        hist_pass<<<128, 256, 0, stream>>>(imp, N, p, state, hist4);
        scan_byte<<<1, 256, 0, stream>>>(hist4, kkeep, p, state);
    }
    prune_mask_ab<<<(N + 255) / 256, 256, 0, stream>>>(A, imp, state, N, Ab);

    // ---- stage-2 setup (B tail and imp regions dead now)
    seg_build<<<dim3((nb16 + 256) / 256, 27), 256, 0, stream>>>(rb2_out, cnt2, P2, nb16, 16, segs16);
    for (int w = 0; w < 4; w++)
        prepack_w<<<14, 256, 0, stream>>>(Wb2 + (size_t)w * 27 * 1024, 27, 32, 27, pack2 + (size_t)w * 27648);
    prepack_w<<<7, 256, 0, stream>>>(Wd, 27, 16, 14, packd);
    hipMemsetAsync((char*)Ab + (size_t)N * 32, 0, 32, stream);   // Ab zero row
    hipMemsetAsync((char*)Db + (size_t)n2 * 64, 0, 64, stream);  // Db zero row
    hipMemsetAsync((char*)Eb + (size_t)n2 * 64, 0, 64, stream);  // Eb zero row
    hipMemsetAsync(INV, 0xFF, (size_t)27 * n2 * 4, stream);
    inv_build<<<dim3((Pd + 255) / 256, 27), 256, 0, stream>>>(rbd_in, rbd_out, cntd, Pd, n2, INV);

    // ---- strided downsample 16->32 (MFMA, bf16 in/out) + BN -> Db
    hipMemsetAsync(stats, 0, 64 * 4, stream);
    conv_mfma_inv16<<<gm2, 256, 0, stream>>>(Ab, packd, INV, n2, N, Db, stats);
    bn_apply_b<32><<<gew, 256, 0, stream>>>(Db, stats, g_d, b_d, n2, Db);

    // ---- conv2: 2x SparseBasicBlock @32 (MFMA tile-inverse, bf16 features)
    for (int i = 0; i < 2; i++) {
        const short* P0 = pack2 + (size_t)(i * 2 + 0) * 27648;
        const short* P1w = pack2 + (size_t)(i * 2 + 1) * 27648;
        hipMemsetAsync(stats, 0, 64 * 4, stream);
        conv_mfma_t16<true><<<gmt, 256, 0, stream>>>(Db, P0, rb2_in, rb2_out, segs16, P2, nb16, n2, Eb, stats);
        bn_apply_b<32><<<gew, 256, 0, stream>>>(Eb, stats, gb2 + (i * 2 + 0) * 32, beb2 + (i * 2 + 0) * 32, n2, Eb);
        hipMemsetAsync(stats, 0, 64 * 4, stream);
        if (i == 0) {
            conv_mfma_t16<true><<<gmt, 256, 0, stream>>>(Eb, P1w, rb2_in, rb2_out, segs16, P2, nb16, n2, OUTb, stats);
            bn_addrelu_x<32, true, true><<<gew, 256, 0, stream>>>(OUTb, Db, stats, gb2 + 32, beb2 + 32, n2, Db);
        } else {
            conv_mfma_t16<false><<<gmt, 256, 0, stream>>>(Eb, P1w, rb2_in, rb2_out, segs16, P2, nb16, n2, OUT, stats);
            bn_addrelu_x<32, false, false><<<gew, 256, 0, stream>>>(OUT, Db, stats, gb2 + 96, beb2 + 96, n2, OUT);
        }
    }
}

// Round 13
// 1285.371 us; speedup vs baseline: 1.7723x; 1.7723x over previous
//
#include <hip/hip_runtime.h>

// ---------------------------------------------------------------------------
// Sparse 3D conv backbone.  (Verbatim revert to round-7 kernel: best measured
// passing configuration, 1282 us.)
// Stage 1 (fp32, bit-exact mask): conv_input 5->16 + BN + ReLU, 2x BasicBlock
//   @16 (rb1, wave-tile gather), prune conv 16->1 + sigmoid, exact top-k via
//   4-pass byte radix.
// Stage 2 (bf16 MFMA, bf16 feature buffers): strided conv 16->32 (dense
//   inverse map), 2x BasicBlock @32 (rb2). BN fused stats + bf16 outputs.
// All gather convs use XCD-aware bijective block swizzle (L2 locality).
// ---------------------------------------------------------------------------

typedef __attribute__((ext_vector_type(8))) short bf16x8;
typedef __attribute__((ext_vector_type(4))) float f32x4;

static __device__ __forceinline__ unsigned f2bfu(float x) {   // fp32->bf16 RNE
    unsigned b = __float_as_uint(x);
    return (b + 0x7FFFu + ((b >> 16) & 1u)) >> 16;
}
static __device__ __forceinline__ float bf2f(unsigned short u) {
    return __uint_as_float(((unsigned)u) << 16);
}
// bijective XCD swizzle: round-robin dispatch -> contiguous chunk per XCD
static __device__ __forceinline__ int xcd_swz(int bid, int nwg) {
    if (nwg < 16) return bid;
    int q = nwg >> 3, r = nwg & 7;
    int x = bid & 7, i = bid >> 3;
    return (x < r ? x * (q + 1) : r * (q + 1) + (x - r) * q) + i;
}

__global__ void rb_count_kernel(const int* __restrict__ rout, int P, int n_out,
                                int* __restrict__ cnt) {
    int k = threadIdx.x;
    if (k >= 27) return;
    const int* r = rout + (size_t)k * P;
    int lo = 0, hi = P;
    while (lo < hi) {
        int mid = (lo + hi) >> 1;
        if (r[mid] < n_out) lo = mid + 1; else hi = mid;
    }
    cnt[k] = lo;
}

// segs[k][b] = lower_bound(rout[k], b*gran), b in [0, nb]
__global__ void seg_build(const int* __restrict__ rout, const int* __restrict__ cnt,
                          int P, int nb, int gran, int* __restrict__ segs) {
    const int k = blockIdx.y;
    const int b = blockIdx.x * 256 + threadIdx.x;
    if (b > nb) return;
    const int target = b * gran;
    const int* r = rout + (size_t)k * P;
    int lo = 0, hi = cnt[k];
    while (lo < hi) {
        int m = (lo + hi) >> 1;
        if (r[m] < target) lo = m + 1; else hi = m;
    }
    segs[k * (nb + 1) + b] = lo;
}

__global__ void inv_build(const int* __restrict__ rin, const int* __restrict__ rout,
                          const int* __restrict__ cnt, int P, int n_out,
                          int* __restrict__ inv) {
    const int k = blockIdx.y;
    const int p = blockIdx.x * 256 + threadIdx.x;
    if (p < cnt[k])
        inv[(size_t)k * n_out + rout[(size_t)k * P + p]] = rin[(size_t)k * P + p];
}

// Pre-pack fp32 weights [T][CI][32] into MFMA B-frag bf16 order.
__global__ void prepack_w(const float* __restrict__ W, int T, int CI, int S,
                          short* __restrict__ pack) {
    int idx = blockIdx.x * 256 + threadIdx.x;     // over S*128
    if (idx >= S * 128) return;
    int l = idx & 63, h = (idx >> 6) & 1, s = idx >> 7;
    int co = (l & 15) + 16 * h;
#pragma unroll
    for (int j = 0; j < 8; j++) {
        int gk = s * 32 + (l >> 4) * 8 + j;
        int tap = gk / CI, cin = gk % CI;
        float w = (tap < T) ? W[((size_t)tap * CI + cin) * 32 + co] : 0.f;
        pack[(size_t)idx * 8 + j] = (short)f2bfu(w);
    }
}

// ---- MFMA gather conv, sorted rulebook, bf16 feat rows [n][32] ------------
template <bool OUT_BF16>
__global__ __launch_bounds__(256) void conv_mfma_sorted32(
        const unsigned short* __restrict__ feat, const short* __restrict__ Bp,
        const int* __restrict__ rin, const int* __restrict__ rout,
        const int* __restrict__ segs, int P, int nb16, int n_out,
        void* __restrict__ outv, float* __restrict__ stats) {
    __shared__ int invw[64];
    __shared__ float part[2][4][32];
    const int t = threadIdx.x, wv = t >> 6, lane = t & 63;
    const int row = lane & 15, grp = lane >> 4;
    const int bid = xcd_swz(blockIdx.x, gridDim.x);
    float ss0 = 0.f, qq0 = 0.f, ss1 = 0.f, qq1 = 0.f;

    for (int tile = 0; tile < 4; ++tile) {
        const int rowbase = bid * 256 + wv * 64 + tile * 16;
        if (rowbase >= n_out) break;
        const int tix = rowbase >> 4;
        int segv = 0;
        if (lane < 28)      segv = segs[lane * (nb16 + 1) + tix];
        else if (lane < 56) segv = segs[(lane - 28) * (nb16 + 1) + tix + 1];
        f32x4 d0 = {0.f, 0.f, 0.f, 0.f}, d1 = {0.f, 0.f, 0.f, 0.f};
        for (int k = 0; k < 27; ++k) {
            const int s0 = __shfl(segv, k);
            const int s1 = __shfl(segv, 28 + k);
            if (s0 == s1) continue;               // wave-uniform skip
            if (lane < 16) invw[wv * 16 + lane] = -1;
            const int e = s0 + lane;
            if (lane < 16 && e < s1)              // segment len <= 16
                invw[wv * 16 + (rout[(size_t)k * P + e] - rowbase)] = rin[(size_t)k * P + e];
            asm volatile("s_waitcnt lgkmcnt(0)" ::: "memory");
            const int rn = invw[wv * 16 + row];
            union { int u[4]; bf16x8 v; } ua;
            ua.u[0] = ua.u[1] = ua.u[2] = ua.u[3] = 0;
            if (rn >= 0)
                ua.v = *(const bf16x8*)(feat + (size_t)rn * 32 + grp * 8);
            const bf16x8 b0 = *(const bf16x8*)(Bp + ((size_t)(2 * k) * 64 + lane) * 8);
            const bf16x8 b1 = *(const bf16x8*)(Bp + ((size_t)(2 * k + 1) * 64 + lane) * 8);
            d0 = __builtin_amdgcn_mfma_f32_16x16x32_bf16(ua.v, b0, d0, 0, 0, 0);
            d1 = __builtin_amdgcn_mfma_f32_16x16x32_bf16(ua.v, b1, d1, 0, 0, 0);
        }
        const int m0 = rowbase + grp * 4;
#pragma unroll
        for (int i = 0; i < 4; i++) {
            if (m0 + i < n_out) {
                if (OUT_BF16) {
                    unsigned short* o = (unsigned short*)outv;
                    o[(size_t)(m0 + i) * 32 + row]      = (unsigned short)f2bfu(d0[i]);
                    o[(size_t)(m0 + i) * 32 + row + 16] = (unsigned short)f2bfu(d1[i]);
                } else {
                    float* o = (float*)outv;
                    o[(size_t)(m0 + i) * 32 + row]      = d0[i];
                    o[(size_t)(m0 + i) * 32 + row + 16] = d1[i];
                }
            }
            ss0 += d0[i]; qq0 += d0[i] * d0[i];
            ss1 += d1[i]; qq1 += d1[i] * d1[i];
        }
    }
#pragma unroll
    for (int d = 16; d <= 32; d <<= 1) {
        ss0 += __shfl_xor(ss0, d); qq0 += __shfl_xor(qq0, d);
        ss1 += __shfl_xor(ss1, d); qq1 += __shfl_xor(qq1, d);
    }
    if (lane < 16) {
        part[0][wv][row] = ss0; part[0][wv][row + 16] = ss1;
        part[1][wv][row] = qq0; part[1][wv][row + 16] = qq1;
    }
    __syncthreads();
    if (t < 64) {
        const int which = t >> 5, co = t & 31;
        atomicAdd(&stats[which * 32 + co],
                  part[which][0][co] + part[which][1][co] +
                  part[which][2][co] + part[which][3][co]);
    }
}

// ---- MFMA gather conv, dense inverse map, CIN=16 (2 taps/step) COUT=32 ----
__global__ __launch_bounds__(256) void conv_mfma_inv16(
        const unsigned short* __restrict__ feat, const short* __restrict__ Bp,
        const int* __restrict__ inv, int n_out,
        unsigned short* __restrict__ out, float* __restrict__ stats) {
    __shared__ float part[2][4][32];
    const int t = threadIdx.x, wv = t >> 6, lane = t & 63;
    const int row = lane & 15, grp = lane >> 4;
    const int bid = xcd_swz(blockIdx.x, gridDim.x);
    float ss0 = 0.f, qq0 = 0.f, ss1 = 0.f, qq1 = 0.f;

    for (int tile = 0; tile < 4; ++tile) {
        const int rowbase = bid * 256 + wv * 64 + tile * 16;
        if (rowbase >= n_out) break;
        const int j = rowbase + row;
        const bool jv = j < n_out;
        f32x4 d0 = {0.f, 0.f, 0.f, 0.f}, d1 = {0.f, 0.f, 0.f, 0.f};
        for (int s = 0; s < 14; ++s) {
            const int tap = 2 * s + (grp >> 1);
            const int cin0 = (grp & 1) * 8;
            int rn = -1;
            if (tap < 27 && jv) rn = inv[(size_t)tap * n_out + j];
            union { int u[4]; bf16x8 v; } ua;
            ua.u[0] = ua.u[1] = ua.u[2] = ua.u[3] = 0;
            if (rn >= 0)
                ua.v = *(const bf16x8*)(feat + (size_t)rn * 16 + cin0);
            const bf16x8 b0 = *(const bf16x8*)(Bp + ((size_t)(2 * s) * 64 + lane) * 8);
            const bf16x8 b1 = *(const bf16x8*)(Bp + ((size_t)(2 * s + 1) * 64 + lane) * 8);
            d0 = __builtin_amdgcn_mfma_f32_16x16x32_bf16(ua.v, b0, d0, 0, 0, 0);
            d1 = __builtin_amdgcn_mfma_f32_16x16x32_bf16(ua.v, b1, d1, 0, 0, 0);
        }
        const int m0 = rowbase + grp * 4;
#pragma unroll
        for (int i = 0; i < 4; i++) {
            if (m0 + i < n_out) {
                out[(size_t)(m0 + i) * 32 + row]      = (unsigned short)f2bfu(d0[i]);
                out[(size_t)(m0 + i) * 32 + row + 16] = (unsigned short)f2bfu(d1[i]);
            }
            ss0 += d0[i]; qq0 += d0[i] * d0[i];
            ss1 += d1[i]; qq1 += d1[i] * d1[i];
        }
    }
#pragma unroll
    for (int d = 16; d <= 32; d <<= 1) {
        ss0 += __shfl_xor(ss0, d); qq0 += __shfl_xor(qq0, d);
        ss1 += __shfl_xor(ss1, d); qq1 += __shfl_xor(qq1, d);
    }
    if (lane < 16) {
        part[0][wv][row] = ss0; part[0][wv][row + 16] = ss1;
        part[1][wv][row] = qq0; part[1][wv][row + 16] = qq1;
    }
    __syncthreads();
    if (t < 64) {
        const int which = t >> 5, co = t & 31;
        atomicAdd(&stats[which * 32 + co],
                  part[which][0][co] + part[which][1][co] +
                  part[which][2][co] + part[which][3][co]);
    }
}

// ---- fp32 wave-tile gather conv, CIN=16 (rb1 chain + prune conv) ----------
template <int COUT, bool SIGMOID, bool STATS>
__global__ __launch_bounds__(256) void conv16_wave(
        const float* __restrict__ feat, const float* __restrict__ W,
        const int* __restrict__ rin, const int* __restrict__ rout,
        const int* __restrict__ segs, int P, int nb64, int n_out,
        float* __restrict__ out, float* __restrict__ stats) {
    __shared__ int invw[4 * 64];
    __shared__ float part[2][4][COUT];
    const int t = threadIdx.x, wv = t >> 6, lane = t & 63;
    const int bid = xcd_swz(blockIdx.x, gridDim.x);
    const int rowbase = bid * 256 + wv * 64;
    const bool active = rowbase < n_out;
    float acc[COUT];
#pragma unroll
    for (int co = 0; co < COUT; co++) acc[co] = 0.f;

    if (active) {
        const int tix = rowbase >> 6;
        int segv = 0;
        if (lane < 28)      segv = segs[lane * (nb64 + 1) + tix];
        else if (lane < 56) segv = segs[(lane - 28) * (nb64 + 1) + tix + 1];
        for (int k = 0; k < 27; ++k) {
            const int s0 = __shfl(segv, k);
            const int s1 = __shfl(segv, 28 + k);
            if (s0 == s1) continue;               // wave-uniform skip
            invw[wv * 64 + lane] = -1;
            const int e = s0 + lane;              // segment len <= 64
            if (e < s1)
                invw[wv * 64 + (rout[(size_t)k * P + e] - rowbase)] = rin[(size_t)k * P + e];
            asm volatile("s_waitcnt lgkmcnt(0)" ::: "memory");
            const int rn = invw[wv * 64 + lane];
            float f[16];
#pragma unroll
            for (int ci = 0; ci < 16; ci++) f[ci] = 0.f;
            if (rn >= 0) {
                const float* fr = feat + (size_t)rn * 16;
#pragma unroll
                for (int q = 0; q < 4; q++) {
                    const float4 v = *(const float4*)(fr + 4 * q);
                    f[4 * q] = v.x; f[4 * q + 1] = v.y;
                    f[4 * q + 2] = v.z; f[4 * q + 3] = v.w;
                }
            }
            const float* __restrict__ Wk = W + k * 16 * COUT;   // lane-uniform
#pragma unroll
            for (int ci = 0; ci < 16; ci++) {
                const float fv = f[ci];
#pragma unroll
                for (int co = 0; co < COUT; co++)
                    acc[co] = fmaf(fv, Wk[ci * COUT + co], acc[co]);
            }
        }
        const int j = rowbase + lane;
        if (j < n_out) {
#pragma unroll
            for (int co = 0; co < COUT; co++) {
                float v = acc[co];
                if (SIGMOID) v = 1.f / (1.f + expf(-v));
                out[(size_t)j * COUT + co] = v;
            }
        }
    }
    if (STATS) {
#pragma unroll
        for (int co = 0; co < COUT; co++) {
            float s = acc[co], s2 = s * s;
#pragma unroll
            for (int d = 1; d < 64; d <<= 1) {
                s += __shfl_xor(s, d);
                s2 += __shfl_xor(s2, d);
            }
            if (lane == 0) { part[0][wv][co] = s; part[1][wv][co] = s2; }
        }
        __syncthreads();
        if (t < 2 * COUT) {
            const int which = t / COUT, co = t - which * COUT;
            atomicAdd(&stats[which * COUT + co],
                      part[which][0][co] + part[which][1][co] +
                      part[which][2][co] + part[which][3][co]);
        }
    }
}

// ---- fp32 block gather conv (conv_input 5->16 only) -----------------------
template <int CIN, int COUT>
__global__ __launch_bounds__(256) void conv_gather(
        const float* __restrict__ feat, const float* __restrict__ W,
        const int* __restrict__ rin, const int* __restrict__ rout,
        const int* __restrict__ segs, int P, int n_out,
        float* __restrict__ out, float* __restrict__ stats) {
    __shared__ int2 invl[256];        // {tag k, rin}; valid iff tag == k
    __shared__ int seg[54];
    __shared__ float part[2][4][COUT];
    const int t = threadIdx.x;
    const int bid = xcd_swz(blockIdx.x, gridDim.x);
    const int j0 = bid * 256;
    const int nb1 = gridDim.x + 1;
    if (t < 54) seg[t] = segs[(t >> 1) * nb1 + bid + (t & 1)];
    invl[t] = make_int2(-1, -1);
    float acc[COUT];
#pragma unroll
    for (int co = 0; co < COUT; co++) acc[co] = 0.f;
    __syncthreads();

    for (int k = 0; k < 27; k++) {
        const int s0 = seg[2 * k], s1 = seg[2 * k + 1];
        if (s0 == s1) continue;
        const int idx = s0 + t;
        if (idx < s1)
            invl[rout[(size_t)k * P + idx] - j0] = make_int2(k, rin[(size_t)k * P + idx]);
        __syncthreads();
        const int2 e = invl[t];
        const int in = (e.x == k) ? e.y : -1;
        __syncthreads();

        float f[CIN];
#pragma unroll
        for (int ci = 0; ci < CIN; ci++) f[ci] = 0.f;
        if (in >= 0) {
            const float* fr = feat + (size_t)in * CIN;
#pragma unroll
            for (int ci = 0; ci < CIN; ci++) f[ci] = fr[ci];
        }
        const float* __restrict__ Wk = W + k * CIN * COUT;   // lane-uniform
#pragma unroll
        for (int ci = 0; ci < CIN; ci++) {
            const float fv = f[ci];
#pragma unroll
            for (int co = 0; co < COUT; co++)
                acc[co] = fmaf(fv, Wk[ci * COUT + co], acc[co]);
        }
    }

    const int j = j0 + t;
    if (j < n_out) {
#pragma unroll
        for (int co = 0; co < COUT; co++) out[(size_t)j * COUT + co] = acc[co];
    }
    const int wv = t >> 6, lane = t & 63;
#pragma unroll
    for (int co = 0; co < COUT; co++) {
        float s = acc[co], s2 = s * s;
#pragma unroll
        for (int d = 1; d < 64; d <<= 1) {
            s += __shfl_xor(s, d);
            s2 += __shfl_xor(s2, d);
        }
        if (lane == 0) { part[0][wv][co] = s; part[1][wv][co] = s2; }
    }
    __syncthreads();
    if (t < 2 * COUT) {
        const int which = t / COUT, co = t - which * COUT;
        atomicAdd(&stats[which * COUT + co],
                  part[which][0][co] + part[which][1][co] +
                  part[which][2][co] + part[which][3][co]);
    }
}

template <int C, bool RELU>
__global__ void bn_apply(const float* __restrict__ x, const float* __restrict__ stats,
                         const float* __restrict__ gg, const float* __restrict__ bb,
                         int n, float* __restrict__ y) {
    const float nf = (float)n;
    const long long total = (long long)n * C;
    for (long long idx = (long long)blockIdx.x * blockDim.x + threadIdx.x;
         idx < total; idx += (long long)gridDim.x * blockDim.x) {
        int ch = (int)(idx & (C - 1));
        float m = stats[ch] / nf;
        float v = stats[C + ch] / nf - m * m;
        float r = rsqrtf(v + 1e-3f);
        float val = gg[ch] * (x[idx] - m) * r + bb[ch];
        if (RELU) val = fmaxf(val, 0.f);
        y[idx] = val;
    }
}

template <int C>
__global__ void bn_apply_addrelu(const float* __restrict__ x,
                                 const float* __restrict__ skip,
                                 const float* __restrict__ stats,
                                 const float* __restrict__ gg,
                                 const float* __restrict__ bb,
                                 int n, float* __restrict__ y) {
    const float nf = (float)n;
    const long long total = (long long)n * C;
    for (long long idx = (long long)blockIdx.x * blockDim.x + threadIdx.x;
         idx < total; idx += (long long)gridDim.x * blockDim.x) {
        int ch = (int)(idx & (C - 1));
        float m = stats[ch] / nf;
        float v = stats[C + ch] / nf - m * m;
        float r = rsqrtf(v + 1e-3f);
        float val = gg[ch] * (x[idx] - m) * r + bb[ch] + skip[idx];
        y[idx] = fmaxf(val, 0.f);
    }
}

// BN over bf16 in -> bf16 out (stage-2 feature buffers)
template <int C>
__global__ void bn_apply_b(const unsigned short* __restrict__ x,
                           const float* __restrict__ stats,
                           const float* __restrict__ gg, const float* __restrict__ bb,
                           int n, unsigned short* __restrict__ y) {
    const float nf = (float)n;
    const long long total = (long long)n * C;
    for (long long idx = (long long)blockIdx.x * blockDim.x + threadIdx.x;
         idx < total; idx += (long long)gridDim.x * blockDim.x) {
        int ch = (int)(idx & (C - 1));
        float m = stats[ch] / nf;
        float v = stats[C + ch] / nf - m * m;
        float r = rsqrtf(v + 1e-3f);
        float val = gg[ch] * (bf2f(x[idx]) - m) * r + bb[ch];
        val = fmaxf(val, 0.f);
        y[idx] = (unsigned short)f2bfu(val);
    }
}

// BN(x fp32) + bf16 skip + ReLU -> bf16 (next block input) or fp32 (final out)
template <int C, bool OUT_BF16>
__global__ void bn_addrelu_sb(const float* __restrict__ x,
                              const unsigned short* __restrict__ skip,
                              const float* __restrict__ stats,
                              const float* __restrict__ gg,
                              const float* __restrict__ bb,
                              int n, void* __restrict__ yv) {
    const float nf = (float)n;
    const long long total = (long long)n * C;
    for (long long idx = (long long)blockIdx.x * blockDim.x + threadIdx.x;
         idx < total; idx += (long long)gridDim.x * blockDim.x) {
        int ch = (int)(idx & (C - 1));
        float m = stats[ch] / nf;
        float v = stats[C + ch] / nf - m * m;
        float r = rsqrtf(v + 1e-3f);
        float val = gg[ch] * (x[idx] - m) * r + bb[ch] + bf2f(skip[idx]);
        val = fmaxf(val, 0.f);
        if (OUT_BF16) ((unsigned short*)yv)[idx] = (unsigned short)f2bfu(val);
        else          ((float*)yv)[idx] = val;
    }
}

// ---- exact top-k: 4-pass byte radix, LDS-privatized histograms ------------
__global__ __launch_bounds__(256) void hist_pass(const float* __restrict__ imp, int n,
                                                 int pass, const int* __restrict__ state,
                                                 int* __restrict__ hist) {
    __shared__ int lh[256];
    const int t = threadIdx.x;
    lh[t] = 0;
    __syncthreads();
    const int shift = 24 - 8 * pass;
    unsigned prefix = 0;
    if (pass > 0) prefix = (unsigned)state[0];
    for (int i = blockIdx.x * 256 + t; i < n; i += gridDim.x * 256) {
        unsigned u = __float_as_uint(imp[i]);
        if (pass == 0 || (u >> (shift + 8)) == prefix)
            atomicAdd(&lh[(u >> shift) & 0xFFu], 1);
    }
    __syncthreads();
    if (lh[t]) atomicAdd(&hist[pass * 256 + t], lh[t]);
}

__global__ __launch_bounds__(256) void scan_byte(const int* __restrict__ hist,
                                                 int kkeep, int pass,
                                                 int* __restrict__ state) {
    __shared__ int h[256];
    const int t = threadIdx.x;
    h[t] = hist[pass * 256 + t];
    __syncthreads();
    if (t == 0) {
        const int target = (pass == 0) ? kkeep : state[1];
        int acc = 0; int b = 255;
        for (; b > 0; b--) {
            if (acc + h[b] >= target) break;
            acc += h[b];
        }
        unsigned prefix = (pass == 0) ? 0u : (unsigned)state[0];
        prefix = (prefix << 8) | (unsigned)b;
        state[0] = (int)prefix;
        state[1] = target - acc;
        if (pass == 3) state[2] = (int)prefix;   // exact bits of kth largest
    }
}

// prune + emit bf16 pruned features (Ab) in one pass; fp32 A dies here
__global__ void prune_mask_ab(const float* __restrict__ x, const float* __restrict__ imp,
                              const int* __restrict__ state, int n,
                              unsigned short* __restrict__ ab) {
    const unsigned K = (unsigned)state[2];
    int i = blockIdx.x * blockDim.x + threadIdx.x;
    if (i >= n) return;
    float im = imp[i];
    float mult = (__float_as_uint(im) >= K) ? im : 0.f;
#pragma unroll
    for (int c = 0; c < 16; c++)
        ab[(size_t)i * 16 + c] = (unsigned short)f2bfu(x[(size_t)i * 16 + c] * mult);
}

extern "C" void kernel_launch(void* const* d_in, const int* in_sizes, int n_in,
                              void* d_out, int out_size, void* d_ws, size_t ws_size,
                              hipStream_t stream) {
    const float* vf    = (const float*)d_in[0];
    const float* W_in  = (const float*)d_in[1];
    const float* g_in  = (const float*)d_in[2];
    const float* b_in  = (const float*)d_in[3];
    const float* Wb1   = (const float*)d_in[4];
    const float* gb1   = (const float*)d_in[6];
    const float* beb1  = (const float*)d_in[7];
    const float* Wp    = (const float*)d_in[8];
    const float* Wd    = (const float*)d_in[9];
    const float* g_d   = (const float*)d_in[10];
    const float* b_d   = (const float*)d_in[11];
    const float* Wb2   = (const float*)d_in[12];
    const float* gb2   = (const float*)d_in[14];
    const float* beb2  = (const float*)d_in[15];
    const int* rb1_in  = (const int*)d_in[16];
    const int* rb1_out = (const int*)d_in[17];
    const int* rbd_in  = (const int*)d_in[18];
    const int* rbd_out = (const int*)d_in[19];
    const int* rb2_in  = (const int*)d_in[20];
    const int* rb2_out = (const int*)d_in[21];

    const int N  = in_sizes[0] / 5;
    const int P1 = in_sizes[16] / 27;
    const int Pd = in_sizes[18] / 27;
    const int P2 = in_sizes[20] / 27;
    const int n2 = out_size / 32;
    const int kkeep = N - N / 2;

    const int gs1   = (N + 255) / 256;        // 256-row blocks over N
    const int gm2   = (n2 + 255) / 256;       // 256-row MFMA blocks over n2
    const int nb64  = (N + 63) / 64;          // 64-row tiles over N
    const int nb16  = (n2 + 15) / 16;         // 16-row tiles over n2
    const int gew   = 2048;

    // workspace layout (4-byte words); regions 16B-aligned
    auto pad4 = [](size_t v) { return (v + 3) & ~(size_t)3; };
    float* A     = (float*)d_ws;                       // N x 16 fp32 (stage 1)
    float* B     = A   + pad4((size_t)N * 16);         // N x 16 fp32 (Ab later)
    float* imp   = B   + pad4((size_t)N * 16);         // N (packs later)
    float* INVf  = imp + pad4((size_t)N);              // 27*n2 ints: invd
    float* Dbf   = INVf + pad4((size_t)n2 * 27);       // 16n2 words: Db bf16 [n2][32]
    float* Ebf   = Dbf + pad4((size_t)n2 * 16);        // 16n2 words: Eb bf16 [n2][32]
    float* stats = Ebf + pad4((size_t)n2 * 16);        // 64
    int*   cnt1  = (int*)(stats + 64);
    int*   cntd  = cnt1 + 32;
    int*   cnt2  = cntd + 32;
    int*   hist4 = cnt2 + 32;                          // 4 * 256
    int*   state = hist4 + 1024;                       // 8
    int*   segs1 = state + 8;                          // 27 * (gs1+1)
    int*   segs64 = segs1 + 27 * (gs1 + 1);            // 27 * (nb64+1)
    int*   INV    = (int*)INVf;                        // invd (rbd dense inverse)
    unsigned short* Ab = (unsigned short*)B;           // N x 16 bf16 (B dead)
    int*   segs16 = (int*)(B + pad4((size_t)N * 8));   // 27*(nb16+1) (B tail)
    short* pack2  = (short*)imp;                       // 4 * 27648 shorts (imp dead)
    short* packd  = pack2 + 4 * 27648;                 // 14336 shorts
    unsigned short* Db = (unsigned short*)Dbf;
    unsigned short* Eb = (unsigned short*)Ebf;
    float* OUT   = (float*)d_out;
    unsigned short* OUTb = (unsigned short*)d_out;     // bf16 scratch in d_out
    float* C2    = OUT;                                // stage-1 scratch (16N <= 32n2)

    rb_count_kernel<<<1, 32, 0, stream>>>(rb1_out, P1, N,  cnt1);
    rb_count_kernel<<<1, 32, 0, stream>>>(rbd_out, Pd, n2, cntd);
    rb_count_kernel<<<1, 32, 0, stream>>>(rb2_out, P2, n2, cnt2);
    seg_build<<<dim3((gs1 + 256) / 256, 27), 256, 0, stream>>>(rb1_out, cnt1, P1, gs1, 256, segs1);
    seg_build<<<dim3((nb64 + 256) / 256, 27), 256, 0, stream>>>(rb1_out, cnt1, P1, nb64, 64, segs64);

    // ---- stage 1 (fp32): conv_input + BN + ReLU -> A
    hipMemsetAsync(stats, 0, 64 * 4, stream);
    conv_gather<5, 16><<<gs1, 256, 0, stream>>>(vf, W_in, rb1_in, rb1_out, segs1, P1, N, B, stats);
    bn_apply<16, true><<<gew, 256, 0, stream>>>(B, stats, g_in, b_in, N, A);

    for (int i = 0; i < 2; i++) {
        const float* W0 = Wb1 + (size_t)(i * 2 + 0) * 27 * 256;
        const float* W1 = Wb1 + (size_t)(i * 2 + 1) * 27 * 256;
        hipMemsetAsync(stats, 0, 64 * 4, stream);
        conv16_wave<16, false, true><<<gs1, 256, 0, stream>>>(A, W0, rb1_in, rb1_out, segs64, P1, nb64, N, B, stats);
        bn_apply<16, true><<<gew, 256, 0, stream>>>(B, stats, gb1 + (i * 2 + 0) * 16, beb1 + (i * 2 + 0) * 16, N, B);
        hipMemsetAsync(stats, 0, 64 * 4, stream);
        conv16_wave<16, false, true><<<gs1, 256, 0, stream>>>(B, W1, rb1_in, rb1_out, segs64, P1, nb64, N, C2, stats);
        bn_apply_addrelu<16><<<gew, 256, 0, stream>>>(C2, A, stats, gb1 + (i * 2 + 1) * 16, beb1 + (i * 2 + 1) * 16, N, A);
    }

    // ---- pruning: imp = sigmoid(conv 16->1); exact top-k via byte radix
    conv16_wave<1, true, false><<<gs1, 256, 0, stream>>>(A, Wp, rb1_in, rb1_out, segs64, P1, nb64, N, imp, stats);
    hipMemsetAsync(hist4, 0, 1024 * 4, stream);
    for (int p = 0; p < 4; p++) {
        hist_pass<<<128, 256, 0, stream>>>(imp, N, p, state, hist4);
        scan_byte<<<1, 256, 0, stream>>>(hist4, kkeep, p, state);
    }
    prune_mask_ab<<<(N + 255) / 256, 256, 0, stream>>>(A, imp, state, N, Ab);

    // ---- stage-2 setup (B tail and imp regions are dead now)
    seg_build<<<dim3((nb16 + 256) / 256, 27), 256, 0, stream>>>(rb2_out, cnt2, P2, nb16, 16, segs16);
    for (int w = 0; w < 4; w++)
        prepack_w<<<14, 256, 0, stream>>>(Wb2 + (size_t)w * 27 * 1024, 27, 32, 27, pack2 + (size_t)w * 27648);
    prepack_w<<<7, 256, 0, stream>>>(Wd, 27, 16, 14, packd);
    hipMemsetAsync(INV, 0xFF, (size_t)27 * n2 * 4, stream);
    inv_build<<<dim3((Pd + 255) / 256, 27), 256, 0, stream>>>(rbd_in, rbd_out, cntd, Pd, n2, INV);

    // ---- strided downsample 16->32 (MFMA, bf16 in/out) + BN -> Db
    hipMemsetAsync(stats, 0, 64 * 4, stream);
    conv_mfma_inv16<<<gm2, 256, 0, stream>>>(Ab, packd, INV, n2, Db, stats);
    bn_apply_b<32><<<gew, 256, 0, stream>>>(Db, stats, g_d, b_d, n2, Db);

    // ---- conv2: 2x SparseBasicBlock @32 (MFMA, bf16 features)
    for (int i = 0; i < 2; i++) {
        const short* P0 = pack2 + (size_t)(i * 2 + 0) * 27648;
        const short* P1w = pack2 + (size_t)(i * 2 + 1) * 27648;
        hipMemsetAsync(stats, 0, 64 * 4, stream);
        conv_mfma_sorted32<true><<<gm2, 256, 0, stream>>>(Db, P0, rb2_in, rb2_out, segs16, P2, nb16, n2, Eb, stats);
        bn_apply_b<32><<<gew, 256, 0, stream>>>(Eb, stats, gb2 + (i * 2 + 0) * 32, beb2 + (i * 2 + 0) * 32, n2, Eb);
        hipMemsetAsync(stats, 0, 64 * 4, stream);
        conv_mfma_sorted32<false><<<gm2, 256, 0, stream>>>(Eb, P1w, rb2_in, rb2_out, segs16, P2, nb16, n2, OUT, stats);
        if (i == 0)
            bn_addrelu_sb<32, true><<<gew, 256, 0, stream>>>(OUT, Db, stats, gb2 + 32, beb2 + 32, n2, Db);
        else
            bn_addrelu_sb<32, false><<<gew, 256, 0, stream>>>(OUT, Db, stats, gb2 + 96, beb2 + 96, n2, OUT);
    }
}